// Round 4
// baseline (136.879 us; speedup 1.0000x reference)
//
#include <hip/hip_runtime.h>

#define SEQ 2048
#define EMB 100
#define BOT 5
#define HSIZE 4096          // power of two, >= 2*SEQ for <=50% load factor
#define SPLIT 16            // gather blocks per row
#define K1T 1024
#define SORTN 2048          // nu <= SEQ = 2048 always

// ---------------- K1: per-row histogram + deterministic sorted compact list ----------------
__global__ __launch_bounds__(K1T) void k1_hist(
    const int* __restrict__ x, const float* __restrict__ idf,
    int* __restrict__ nuniq, int* __restrict__ gkey, float* __restrict__ gcoef)
{
    __shared__ int   hkey[HSIZE];
    __shared__ int   hcnt[HSIZE];
    __shared__ int   ukey[SORTN];
    __shared__ float ucoef[SORTN];
    __shared__ float red[K1T / 64];
    __shared__ int   nu;
    __shared__ float zinv;

    const int b = blockIdx.x, tid = threadIdx.x;
    const int lane = tid & 63, wid = tid >> 6;

    for (int i = tid; i < HSIZE; i += K1T) { hkey[i] = -1; hcnt[i] = 0; }
    if (tid == 0) nu = 0;
    __syncthreads();

    // histogram + Z in deterministic order (fixed stride, fixed reduce tree)
    const int* xrow = x + (size_t)b * SEQ;
    float z = 0.0f;
    for (int s = tid; s < SEQ; s += K1T) {
        int key = xrow[s];
        z += idf[key];                       // Z = sum_s idf[x_s]
        unsigned slot = ((unsigned)key * 2654435761u) >> 20;
        for (;;) {
            int prev = atomicCAS(&hkey[slot], -1, key);
            if (prev == -1 || prev == key) { atomicAdd(&hcnt[slot], 1); break; }
            slot = (slot + 1) & (HSIZE - 1);
        }
    }
    for (int off = 32; off > 0; off >>= 1) z += __shfl_down(z, off);
    if (lane == 0) red[wid] = z;
    __syncthreads();
    if (tid == 0) {
        float t = 0.0f;
        #pragma unroll
        for (int i = 0; i < K1T / 64; ++i) t += red[i];
        zinv = 1.0f / t;
    }
    __syncthreads();
    const float iz = zinv;

    // compact occupied slots (order arbitrary here — sorted below)
    for (int i = tid; i < HSIZE; i += K1T) {
        int k = hkey[i];
        if (k >= 0) {
            float c = (float)hcnt[i];
            int pos = atomicAdd(&nu, 1);
            ukey[pos]  = k;
            ucoef[pos] = c * c * idf[k] * iz;
        }
    }
    __syncthreads();
    const int n = nu;

    // pad then bitonic sort by key (ascending) -> fully deterministic order
    for (int i = tid; i < SORTN; i += K1T)
        if (i >= n) { ukey[i] = 0x7FFFFFFF; ucoef[i] = 0.0f; }
    __syncthreads();

    for (int k = 2; k <= SORTN; k <<= 1) {
        for (int j = k >> 1; j > 0; j >>= 1) {
            for (int i = tid; i < SORTN; i += K1T) {
                int l = i ^ j;
                if (l > i) {
                    int ki = ukey[i], kl = ukey[l];
                    bool asc = ((i & k) == 0);
                    if ((ki > kl) == asc) {
                        ukey[i] = kl; ukey[l] = ki;
                        float t = ucoef[i]; ucoef[i] = ucoef[l]; ucoef[l] = t;
                    }
                }
            }
            __syncthreads();
        }
    }

    for (int i = tid; i < n; i += K1T) {
        gkey [(size_t)b * SEQ + i] = ukey[i];
        gcoef[(size_t)b * SEQ + i] = ucoef[i];
    }
    if (tid == 0) nuniq[b] = n;
}

// ---------------- K2: sliced weighted-embedding gather ----------------
__global__ __launch_bounds__(256) void k2_gather(
    const int* __restrict__ nuniq, const int* __restrict__ gkey,
    const float* __restrict__ gcoef, const float* __restrict__ we,
    float* __restrict__ partial)
{
    __shared__ int   skey[SEQ];
    __shared__ float scoef[SEQ];
    __shared__ float part[2][EMB];

    const int bx  = blockIdx.x;
    const int b   = bx >> 4;              // SPLIT == 16
    const int s   = bx & (SPLIT - 1);
    const int tid = threadIdx.x;
    const int g   = tid >> 7;             // 0 or 1
    const int e   = tid & 127;

    const int nu = nuniq[b];
    const int*   kk = gkey  + (size_t)b * SEQ;
    const float* cc = gcoef + (size_t)b * SEQ;

    for (int i = tid; i < nu; i += 256) { skey[i] = kk[i]; scoef[i] = cc[i]; }
    __syncthreads();

    const int st = SPLIT * 2;             // 32 streams per row
    if (e < EMB) {
        float a0 = 0, a1 = 0, a2 = 0, a3 = 0, a4 = 0, a5 = 0, a6 = 0, a7 = 0;
        int i = s * 2 + g;
        for (; i + 7 * st < nu; i += 8 * st) {
            int   k0 = skey[i],        k1 = skey[i + st],     k2 = skey[i + 2*st], k3 = skey[i + 3*st];
            int   k4 = skey[i + 4*st], k5 = skey[i + 5*st],   k6 = skey[i + 6*st], k7 = skey[i + 7*st];
            float c0 = scoef[i],        c1 = scoef[i + st],   c2 = scoef[i + 2*st], c3 = scoef[i + 3*st];
            float c4 = scoef[i + 4*st], c5 = scoef[i + 5*st], c6 = scoef[i + 6*st], c7 = scoef[i + 7*st];
            a0 += c0 * we[(size_t)k0 * EMB + e];
            a1 += c1 * we[(size_t)k1 * EMB + e];
            a2 += c2 * we[(size_t)k2 * EMB + e];
            a3 += c3 * we[(size_t)k3 * EMB + e];
            a4 += c4 * we[(size_t)k4 * EMB + e];
            a5 += c5 * we[(size_t)k5 * EMB + e];
            a6 += c6 * we[(size_t)k6 * EMB + e];
            a7 += c7 * we[(size_t)k7 * EMB + e];
        }
        for (; i < nu; i += st) a0 += scoef[i] * we[(size_t)skey[i] * EMB + e];
        part[g][e] = ((a0 + a1) + (a2 + a3)) + ((a4 + a5) + (a6 + a7));
    }
    __syncthreads();
    if (tid < EMB) partial[(size_t)bx * EMB + tid] = part[0][tid] + part[1][tid];
}

// ---------------- K3: reduce partials + tiny MLP ----------------
__global__ __launch_bounds__(128) void k3_mlp(
    const float* __restrict__ partial,
    const float* __restrict__ fc1w, const float* __restrict__ fc1b,
    const float* __restrict__ fc2w, const float* __restrict__ fc2b,
    float* __restrict__ out)
{
    __shared__ float doc[EMB];
    __shared__ float hsh[BOT];

    const int b = blockIdx.x, tid = threadIdx.x;

    if (tid < EMB) {
        float a = 0.0f;
        const float* p = partial + (size_t)b * SPLIT * EMB + tid;
        #pragma unroll
        for (int s = 0; s < SPLIT; ++s) a += p[s * EMB];
        doc[tid] = a;
    }
    __syncthreads();

    if (tid < BOT) {
        float h = fc1b[tid];
        const float* wr = fc1w + tid * EMB;
        for (int e = 0; e < EMB; ++e) h += doc[e] * wr[e];
        hsh[tid] = h;
    }
    __syncthreads();

    if (tid < EMB) {
        float o = fc2b[tid];
        const float* wr = fc2w + tid * BOT;
        #pragma unroll
        for (int j = 0; j < BOT; ++j) o += hsh[j] * wr[j];
        out[(size_t)b * EMB + tid] = o;
    }
}

extern "C" void kernel_launch(void* const* d_in, const int* in_sizes, int n_in,
                              void* d_out, int out_size, void* d_ws, size_t ws_size,
                              hipStream_t stream) {
    const int*   x    = (const int*)d_in[0];
    const float* we   = (const float*)d_in[1];
    const float* idf  = (const float*)d_in[2];
    const float* fc1w = (const float*)d_in[3];
    const float* fc1b = (const float*)d_in[4];
    const float* fc2w = (const float*)d_in[5];
    const float* fc2b = (const float*)d_in[6];
    float*       out  = (float*)d_out;

    const int B = in_sizes[0] / SEQ;  // 128

    char* ws = (char*)d_ws;
    int*   nuniq   = (int*)ws;                               // B ints
    int*   gkey    = (int*)(ws + 1024);                      // B*SEQ ints   (1 MB)
    float* gcoef   = (float*)(ws + 1024 + (size_t)B*SEQ*4);  // B*SEQ floats (1 MB)
    float* partial = (float*)(ws + 1024 + (size_t)B*SEQ*8);  // B*SPLIT*EMB floats

    k1_hist  <<<B,         K1T, 0, stream>>>(x, idf, nuniq, gkey, gcoef);
    k2_gather<<<B * SPLIT, 256, 0, stream>>>(nuniq, gkey, gcoef, we, partial);
    k3_mlp   <<<B,         128, 0, stream>>>(partial, fc1w, fc1b, fc2w, fc2b, out);
}

// Round 5
// 106.876 us; speedup vs baseline: 1.2807x; 1.2807x over previous
//
#include <hip/hip_runtime.h>

#define SEQ 2048
#define EMB 100
#define BOT 5
#define HSIZE 4096          // power of two, >= 2*SEQ for <=50% load factor
#define SPLIT 32            // gather blocks per row
#define K1T 1024

// ---------------- K1: per-row hash histogram + per-token coefficients ----------------
// Determinism: hash slot positions race, but per-key COUNTS are race-invariant
// integers; Z is a fixed-order sum; coef[b,s] is a pure per-token function.
__global__ __launch_bounds__(K1T) void k1_hist(
    const int* __restrict__ x, const float* __restrict__ idf,
    float* __restrict__ coef)
{
    __shared__ int   hkey[HSIZE];
    __shared__ int   hcnt[HSIZE];
    __shared__ float red[K1T / 64];
    __shared__ float zinv;

    const int b = blockIdx.x, tid = threadIdx.x;
    const int lane = tid & 63, wid = tid >> 6;

    for (int i = tid; i < HSIZE; i += K1T) { hkey[i] = -1; hcnt[i] = 0; }
    __syncthreads();

    const int* xrow = x + (size_t)b * SEQ;

    // build histogram + Z (fixed per-thread order + fixed reduction tree)
    int   mykey[SEQ / K1T];
    float myidf[SEQ / K1T];
    float z = 0.0f;
    #pragma unroll
    for (int j = 0; j < SEQ / K1T; ++j) {
        int s   = tid + j * K1T;
        int key = xrow[s];
        float w = idf[key];
        mykey[j] = key;
        myidf[j] = w;
        z += w;
        unsigned slot = ((unsigned)key * 2654435761u) >> 20;
        for (;;) {
            int prev = atomicCAS(&hkey[slot], -1, key);
            if (prev == -1 || prev == key) { atomicAdd(&hcnt[slot], 1); break; }
            slot = (slot + 1) & (HSIZE - 1);
        }
    }
    for (int off = 32; off > 0; off >>= 1) z += __shfl_down(z, off);
    if (lane == 0) red[wid] = z;
    __syncthreads();
    if (tid == 0) {
        float t = 0.0f;
        #pragma unroll
        for (int i = 0; i < K1T / 64; ++i) t += red[i];
        zinv = 1.0f / t;
    }
    __syncthreads();
    const float iz = zinv;

    // per-token coefficient: cnt * idf * invZ  (lookup by key; counts final)
    #pragma unroll
    for (int j = 0; j < SEQ / K1T; ++j) {
        int s   = tid + j * K1T;
        int key = mykey[j];
        unsigned slot = ((unsigned)key * 2654435761u) >> 20;
        while (hkey[slot] != key) slot = (slot + 1) & (HSIZE - 1);
        coef[(size_t)b * SEQ + s] = (float)hcnt[slot] * myidf[j] * iz;
    }
}

// ---------------- K2: sliced weighted-embedding gather (per-token) ----------------
__global__ __launch_bounds__(256) void k2_gather(
    const int* __restrict__ x, const float* __restrict__ coef,
    const float* __restrict__ we, float* __restrict__ partial)
{
    __shared__ int   skey[SEQ];
    __shared__ float scoef[SEQ];
    __shared__ float part[2][EMB];

    const int bx  = blockIdx.x;
    const int b   = bx / SPLIT;
    const int sp  = bx % SPLIT;
    const int tid = threadIdx.x;
    const int g   = tid >> 7;             // 0 or 1
    const int e   = tid & 127;

    const int*   kk = x    + (size_t)b * SEQ;
    const float* cc = coef + (size_t)b * SEQ;
    for (int i = tid; i < SEQ; i += 256) { skey[i] = kk[i]; scoef[i] = cc[i]; }
    __syncthreads();

    const int st = SPLIT * 2;             // 64 streams per row
    if (e < EMB) {
        float a0 = 0, a1 = 0, a2 = 0, a3 = 0, a4 = 0, a5 = 0, a6 = 0, a7 = 0;
        int i = sp * 2 + g;
        for (; i + 7 * st < SEQ; i += 8 * st) {   // SEQ = 64*8*4 -> 4 iters, no tail
            int   k0 = skey[i],        k1 = skey[i + st],     k2 = skey[i + 2*st], k3 = skey[i + 3*st];
            int   k4 = skey[i + 4*st], k5 = skey[i + 5*st],   k6 = skey[i + 6*st], k7 = skey[i + 7*st];
            float c0 = scoef[i],        c1 = scoef[i + st],   c2 = scoef[i + 2*st], c3 = scoef[i + 3*st];
            float c4 = scoef[i + 4*st], c5 = scoef[i + 5*st], c6 = scoef[i + 6*st], c7 = scoef[i + 7*st];
            a0 += c0 * we[(size_t)k0 * EMB + e];
            a1 += c1 * we[(size_t)k1 * EMB + e];
            a2 += c2 * we[(size_t)k2 * EMB + e];
            a3 += c3 * we[(size_t)k3 * EMB + e];
            a4 += c4 * we[(size_t)k4 * EMB + e];
            a5 += c5 * we[(size_t)k5 * EMB + e];
            a6 += c6 * we[(size_t)k6 * EMB + e];
            a7 += c7 * we[(size_t)k7 * EMB + e];
        }
        for (; i < SEQ; i += st) a0 += scoef[i] * we[(size_t)skey[i] * EMB + e];
        part[g][e] = ((a0 + a1) + (a2 + a3)) + ((a4 + a5) + (a6 + a7));
    }
    __syncthreads();
    if (tid < EMB) partial[(size_t)bx * EMB + tid] = part[0][tid] + part[1][tid];
}

// ---------------- K3: reduce partials + tiny MLP ----------------
__global__ __launch_bounds__(128) void k3_mlp(
    const float* __restrict__ partial,
    const float* __restrict__ fc1w, const float* __restrict__ fc1b,
    const float* __restrict__ fc2w, const float* __restrict__ fc2b,
    float* __restrict__ out)
{
    __shared__ float doc[EMB];
    __shared__ float hsh[BOT];

    const int b = blockIdx.x, tid = threadIdx.x;

    if (tid < EMB) {
        float a = 0.0f;
        const float* p = partial + (size_t)b * SPLIT * EMB + tid;
        #pragma unroll
        for (int s = 0; s < SPLIT; ++s) a += p[s * EMB];
        doc[tid] = a;
    }
    __syncthreads();

    if (tid < BOT) {
        float h = fc1b[tid];
        const float* wr = fc1w + tid * EMB;
        for (int e = 0; e < EMB; ++e) h += doc[e] * wr[e];
        hsh[tid] = h;
    }
    __syncthreads();

    if (tid < EMB) {
        float o = fc2b[tid];
        const float* wr = fc2w + tid * BOT;
        #pragma unroll
        for (int j = 0; j < BOT; ++j) o += hsh[j] * wr[j];
        out[(size_t)b * EMB + tid] = o;
    }
}

extern "C" void kernel_launch(void* const* d_in, const int* in_sizes, int n_in,
                              void* d_out, int out_size, void* d_ws, size_t ws_size,
                              hipStream_t stream) {
    const int*   x    = (const int*)d_in[0];
    const float* we   = (const float*)d_in[1];
    const float* idf  = (const float*)d_in[2];
    const float* fc1w = (const float*)d_in[3];
    const float* fc1b = (const float*)d_in[4];
    const float* fc2w = (const float*)d_in[5];
    const float* fc2b = (const float*)d_in[6];
    float*       out  = (float*)d_out;

    const int B = in_sizes[0] / SEQ;  // 128

    char* ws = (char*)d_ws;
    float* coef    = (float*)ws;                           // B*SEQ floats (1 MB)
    float* partial = (float*)(ws + (size_t)B * SEQ * 4);   // B*SPLIT*EMB floats (1.6 MB)

    k1_hist  <<<B,         K1T, 0, stream>>>(x, idf, coef);
    k2_gather<<<B * SPLIT, 256, 0, stream>>>(x, coef, we, partial);
    k3_mlp   <<<B,         128, 0, stream>>>(partial, fc1w, fc1b, fc2w, fc2b, out);
}

// Round 6
// 103.347 us; speedup vs baseline: 1.3245x; 1.0341x over previous
//
#include <hip/hip_runtime.h>

#define SEQ 2048
#define EMB 100
#define BOT 5
#define HSIZE 4096          // power of two, >= 2*SEQ for <=50% load factor
#define SPLIT 16            // gather blocks per row (contiguous 128-token chunks)
#define CHUNK (SEQ / SPLIT) // 128 tokens per k2 block
#define K1T 1024

// ---------------- K1: per-row hash histogram + per-token coefficients ----------------
// Determinism: hash slot positions race, but per-key COUNTS are race-invariant
// integers; Z is a fixed-order sum; coef[b,s] is a pure per-token function.
__global__ __launch_bounds__(K1T) void k1_hist(
    const int* __restrict__ x, const float* __restrict__ idf,
    float* __restrict__ coef)
{
    __shared__ int   hkey[HSIZE];
    __shared__ int   hcnt[HSIZE];
    __shared__ float red[K1T / 64];
    __shared__ float zinv;

    const int b = blockIdx.x, tid = threadIdx.x;
    const int lane = tid & 63, wid = tid >> 6;

    for (int i = tid; i < HSIZE; i += K1T) { hkey[i] = -1; hcnt[i] = 0; }
    __syncthreads();

    const int* xrow = x + (size_t)b * SEQ;

    int   mykey[SEQ / K1T];
    float myidf[SEQ / K1T];
    float z = 0.0f;
    #pragma unroll
    for (int j = 0; j < SEQ / K1T; ++j) {
        int s   = tid + j * K1T;
        int key = xrow[s];
        float w = idf[key];
        mykey[j] = key;
        myidf[j] = w;
        z += w;
        unsigned slot = ((unsigned)key * 2654435761u) >> 20;
        for (;;) {
            int prev = atomicCAS(&hkey[slot], -1, key);
            if (prev == -1 || prev == key) { atomicAdd(&hcnt[slot], 1); break; }
            slot = (slot + 1) & (HSIZE - 1);
        }
    }
    for (int off = 32; off > 0; off >>= 1) z += __shfl_down(z, off);
    if (lane == 0) red[wid] = z;
    __syncthreads();
    if (tid == 0) {
        float t = 0.0f;
        #pragma unroll
        for (int i = 0; i < K1T / 64; ++i) t += red[i];
        zinv = 1.0f / t;
    }
    __syncthreads();
    const float iz = zinv;

    #pragma unroll
    for (int j = 0; j < SEQ / K1T; ++j) {
        int s   = tid + j * K1T;
        int key = mykey[j];
        unsigned slot = ((unsigned)key * 2654435761u) >> 20;
        while (hkey[slot] != key) slot = (slot + 1) & (HSIZE - 1);
        coef[(size_t)b * SEQ + s] = (float)hcnt[slot] * myidf[j] * iz;
    }
}

// ---------------- K2: chunked weighted-embedding gather (float2 lanes) ----------------
// Block bx handles row b = bx/SPLIT, tokens [sp*CHUNK, (sp+1)*CHUNK).
// 4 waves; wave w owns tokens [w*32, w*32+32) of the chunk, 8 streams in flight.
// Lanes 0..49 each hold a float2 slice of the 100-dim embedding row.
__global__ __launch_bounds__(256) void k2_gather(
    const int* __restrict__ x, const float* __restrict__ coef,
    const float* __restrict__ we, float* __restrict__ partial)
{
    __shared__ int   skey[CHUNK];
    __shared__ float scoef[CHUNK];
    __shared__ float part[4][EMB];

    const int bx   = blockIdx.x;
    const int b    = bx >> 4;             // SPLIT == 16
    const int sp   = bx & (SPLIT - 1);
    const int tid  = threadIdx.x;
    const int wave = tid >> 6;
    const int lane = tid & 63;

    const int base = sp * CHUNK;
    if (tid < CHUNK) {
        skey [tid] = x   [(size_t)b * SEQ + base + tid];
        scoef[tid] = coef[(size_t)b * SEQ + base + tid];
    }
    __syncthreads();

    if (lane < EMB / 2) {
        float2 a0 = {0,0}, a1 = {0,0}, a2 = {0,0}, a3 = {0,0};
        float2 a4 = {0,0}, a5 = {0,0}, a6 = {0,0}, a7 = {0,0};
        const int t0 = wave * 32;
        #pragma unroll
        for (int it = 0; it < 4; ++it) {
            const int i = t0 + it * 8;
            int   k0 = skey[i+0], k1 = skey[i+1], k2 = skey[i+2], k3 = skey[i+3];
            int   k4 = skey[i+4], k5 = skey[i+5], k6 = skey[i+6], k7 = skey[i+7];
            float c0 = scoef[i+0], c1 = scoef[i+1], c2 = scoef[i+2], c3 = scoef[i+3];
            float c4 = scoef[i+4], c5 = scoef[i+5], c6 = scoef[i+6], c7 = scoef[i+7];
            float2 v0 = ((const float2*)(we + (size_t)k0 * EMB))[lane];
            float2 v1 = ((const float2*)(we + (size_t)k1 * EMB))[lane];
            float2 v2 = ((const float2*)(we + (size_t)k2 * EMB))[lane];
            float2 v3 = ((const float2*)(we + (size_t)k3 * EMB))[lane];
            float2 v4 = ((const float2*)(we + (size_t)k4 * EMB))[lane];
            float2 v5 = ((const float2*)(we + (size_t)k5 * EMB))[lane];
            float2 v6 = ((const float2*)(we + (size_t)k6 * EMB))[lane];
            float2 v7 = ((const float2*)(we + (size_t)k7 * EMB))[lane];
            a0.x += c0 * v0.x; a0.y += c0 * v0.y;
            a1.x += c1 * v1.x; a1.y += c1 * v1.y;
            a2.x += c2 * v2.x; a2.y += c2 * v2.y;
            a3.x += c3 * v3.x; a3.y += c3 * v3.y;
            a4.x += c4 * v4.x; a4.y += c4 * v4.y;
            a5.x += c5 * v5.x; a5.y += c5 * v5.y;
            a6.x += c6 * v6.x; a6.y += c6 * v6.y;
            a7.x += c7 * v7.x; a7.y += c7 * v7.y;
        }
        float sx = ((a0.x + a1.x) + (a2.x + a3.x)) + ((a4.x + a5.x) + (a6.x + a7.x));
        float sy = ((a0.y + a1.y) + (a2.y + a3.y)) + ((a4.y + a5.y) + (a6.y + a7.y));
        part[wave][2 * lane]     = sx;
        part[wave][2 * lane + 1] = sy;
    }
    __syncthreads();
    if (tid < EMB)
        partial[(size_t)bx * EMB + tid] =
            (part[0][tid] + part[1][tid]) + (part[2][tid] + part[3][tid]);
}

// ---------------- K3: reduce partials + tiny MLP ----------------
__global__ __launch_bounds__(128) void k3_mlp(
    const float* __restrict__ partial,
    const float* __restrict__ fc1w, const float* __restrict__ fc1b,
    const float* __restrict__ fc2w, const float* __restrict__ fc2b,
    float* __restrict__ out)
{
    __shared__ float doc[EMB];
    __shared__ float hsh[BOT];

    const int b = blockIdx.x, tid = threadIdx.x;

    if (tid < EMB) {
        float a = 0.0f;
        const float* p = partial + (size_t)b * SPLIT * EMB + tid;
        #pragma unroll
        for (int s = 0; s < SPLIT; ++s) a += p[s * EMB];
        doc[tid] = a;
    }
    __syncthreads();

    if (tid < BOT) {
        float h = fc1b[tid];
        const float* wr = fc1w + tid * EMB;
        for (int e = 0; e < EMB; ++e) h += doc[e] * wr[e];
        hsh[tid] = h;
    }
    __syncthreads();

    if (tid < EMB) {
        float o = fc2b[tid];
        const float* wr = fc2w + tid * BOT;
        #pragma unroll
        for (int j = 0; j < BOT; ++j) o += hsh[j] * wr[j];
        out[(size_t)b * EMB + tid] = o;
    }
}

extern "C" void kernel_launch(void* const* d_in, const int* in_sizes, int n_in,
                              void* d_out, int out_size, void* d_ws, size_t ws_size,
                              hipStream_t stream) {
    const int*   x    = (const int*)d_in[0];
    const float* we   = (const float*)d_in[1];
    const float* idf  = (const float*)d_in[2];
    const float* fc1w = (const float*)d_in[3];
    const float* fc1b = (const float*)d_in[4];
    const float* fc2w = (const float*)d_in[5];
    const float* fc2b = (const float*)d_in[6];
    float*       out  = (float*)d_out;

    const int B = in_sizes[0] / SEQ;  // 128

    char* ws = (char*)d_ws;
    float* coef    = (float*)ws;                           // B*SEQ floats (1 MB)
    float* partial = (float*)(ws + (size_t)B * SEQ * 4);   // B*SPLIT*EMB floats

    k1_hist  <<<B,         K1T, 0, stream>>>(x, idf, coef);
    k2_gather<<<B * SPLIT, 256, 0, stream>>>(x, coef, we, partial);
    k3_mlp   <<<B,         128, 0, stream>>>(partial, fc1w, fc1b, fc2w, fc2b, out);
}